// Round 1
// baseline (3285.764 us; speedup 1.0000x reference)
//
#include <hip/hip_runtime.h>
#include <stdint.h>

#define B_SZ 64
#define T_SZ 2048
#define I_SZ 256
#define H_SZ 256

typedef __attribute__((ext_vector_type(8))) short bf16x8_t;
typedef __attribute__((ext_vector_type(4))) float f32x4_t;
typedef __attribute__((ext_vector_type(2))) _Float16 half2_t;

#if defined(__has_builtin)
#if __has_builtin(__builtin_amdgcn_fdot2)
#define HAVE_FDOT2 1
#endif
#endif
#ifndef HAVE_FDOT2
#define HAVE_FDOT2 0
#endif

static __device__ __forceinline__ unsigned short f2bf(float f){
  unsigned int u = __float_as_uint(f);
  return (unsigned short)((u + 0x7fffu + ((u >> 16) & 1u)) >> 16);
}
static __device__ __forceinline__ unsigned short f2h(float f){
  return __builtin_bit_cast(unsigned short, (_Float16)f);
}
static __device__ __forceinline__ float h2f(unsigned short h){
  return (float)__builtin_bit_cast(_Float16, h);
}
static __device__ __forceinline__ unsigned int pkh(float a, float b){
  return (unsigned int)f2h(a) | ((unsigned int)f2h(b) << 16);
}
static __device__ __forceinline__ float dot2acc(unsigned int w, unsigned int h, float acc){
#if HAVE_FDOT2
  return __builtin_amdgcn_fdot2(__builtin_bit_cast(half2_t, w),
                                __builtin_bit_cast(half2_t, h), acc, false);
#else
  half2_t wv = __builtin_bit_cast(half2_t, w);
  half2_t hv = __builtin_bit_cast(half2_t, h);
  acc = fmaf((float)wv.x, (float)hv.x, acc);
  acc = fmaf((float)wv.y, (float)hv.y, acc);
  return acc;
#endif
}
static __device__ __forceinline__ float sigmoidf_(float x){
  return 1.f / (1.f + __expf(-x));
}
static __device__ __forceinline__ float tanhf_(float x){
  float e = __expf(-2.f * fabsf(x));
  float t = (1.f - e) / (1.f + e);
  return copysignf(t, x);
}

// ---------------- pack recurrent weights: f16 pairs along k ----------------
// WP[g][q][j] : uint4 = k-values 8q..8q+7 of row j of gate g (lo half = even k)
__global__ __launch_bounds__(256) void prep_pack(const float* __restrict__ Whr,
                                                 const float* __restrict__ Whz,
                                                 const float* __restrict__ WhN,
                                                 uint4* __restrict__ WP){
  const int g = blockIdx.x;
  const int j = threadIdx.x;
  const float* W = (g == 0) ? Whr : ((g == 1) ? Whz : WhN);
  #pragma unroll 4
  for(int q = 0; q < 32; ++q){
    float4 a = *(const float4*)&W[j*256 + q*8];
    float4 b = *(const float4*)&W[j*256 + q*8 + 4];
    uint4 o;
    o.x = pkh(a.x, a.y);
    o.y = pkh(a.z, a.w);
    o.z = pkh(b.x, b.y);
    o.w = pkh(b.z, b.w);
    WP[(g*32 + q)*256 + j] = o;
  }
}

// ---------------- input projections: [M=131072,K=256] @ W^T[K,256] ----------
// M-tile 64, full N=256 per block, bf16 MFMA 16x16x32.
__global__ __launch_bounds__(256) void proj_kernel(const float* __restrict__ X,
                                                   const float* __restrict__ W,
                                                   const float* __restrict__ bias,
                                                   unsigned short* __restrict__ dst16,
                                                   float* __restrict__ dst32){
  __shared__ unsigned short As[64][72];   // padded to 72 (144B, 16B-aligned rows)
  __shared__ unsigned short Bs[256][72];
  const int tid = threadIdx.x;
  const int m0 = blockIdx.x * 64;
  const int w  = tid >> 6;   // wave 0..3 -> rows w*16..w*16+15
  const int l  = tid & 63;
  const int l15 = l & 15;
  const int lq  = l >> 4;    // 0..3

  f32x4_t acc[16];
  #pragma unroll
  for(int i = 0; i < 16; ++i) acc[i] = (f32x4_t){0.f, 0.f, 0.f, 0.f};

  for(int kc = 0; kc < 256; kc += 64){
    // stage A: 64 rows x 64 k (fp32 -> bf16)
    #pragma unroll
    for(int p = 0; p < 4; ++p){
      int e = 4*(p*256 + tid);
      int r = e >> 6, k = e & 63;
      float4 v = *(const float4*)&X[(size_t)(m0 + r)*256 + kc + k];
      ushort4 sv; sv.x = f2bf(v.x); sv.y = f2bf(v.y); sv.z = f2bf(v.z); sv.w = f2bf(v.w);
      *(ushort4*)&As[r][k] = sv;
    }
    // stage B: 256 rows (output cols) x 64 k
    #pragma unroll
    for(int p = 0; p < 16; ++p){
      int e = 4*(p*256 + tid);
      int n = e >> 6, k = e & 63;
      float4 v = *(const float4*)&W[(size_t)n*256 + kc + k];
      ushort4 sv; sv.x = f2bf(v.x); sv.y = f2bf(v.y); sv.z = f2bf(v.z); sv.w = f2bf(v.w);
      *(ushort4*)&Bs[n][k] = sv;
    }
    __syncthreads();
    #pragma unroll
    for(int ks = 0; ks < 2; ++ks){
      bf16x8_t a = *(const bf16x8_t*)&As[w*16 + l15][ks*32 + lq*8];
      #pragma unroll
      for(int fc = 0; fc < 16; ++fc){
        bf16x8_t bfr = *(const bf16x8_t*)&Bs[fc*16 + l15][ks*32 + lq*8];
        acc[fc] = __builtin_amdgcn_mfma_f32_16x16x32_bf16(a, bfr, acc[fc], 0, 0, 0);
      }
    }
    __syncthreads();
  }
  // epilogue: + bias, store (f16 for r/z paths, fp32 for n path into d_out)
  #pragma unroll
  for(int fc = 0; fc < 16; ++fc){
    int col = fc*16 + l15;
    float bv = bias[col];
    #pragma unroll
    for(int ri = 0; ri < 4; ++ri){
      int row = w*16 + lq*4 + ri;
      size_t idx = (size_t)(m0 + row)*256 + col;
      float v = acc[fc][ri] + bv;
      if(dst32) dst32[idx] = v;
      else      dst16[idx] = f2h(v);
    }
  }
}

// ---------------- recurrence: 1 block per batch, weights register-resident --
// 768 threads = 12 waves. thread (g = tid>>8, j = tid&255) owns weight row j
// of gate g (r=0, z=1, n=2) as 32 x uint4 of packed f16 -> 128 VGPRs.
__global__ __launch_bounds__(768, 1) void scan_kernel(const uint4* __restrict__ WP,
        const unsigned short* __restrict__ xr_all,
        const unsigned short* __restrict__ xz_all,
        float* __restrict__ out, float* __restrict__ hlast,
        const float* __restrict__ bhr, const float* __restrict__ bhz,
        const float* __restrict__ bhN){
  __shared__ __align__(16) unsigned short hs16[256];  // h as f16
  __shared__ float pr[256];
  __shared__ float pz[256];
  const int tid = threadIdx.x;
  const int g = tid >> 8;     // gate: waves 0-3 r, 4-7 z, 8-11 n(+combine)
  const int j = tid & 255;
  const int b = blockIdx.x;

  uint4 wreg[32];
  #pragma unroll
  for(int q = 0; q < 32; ++q) wreg[q] = WP[(g*32 + q)*256 + j];

  const unsigned short* xr_p = xr_all + (size_t)b*T_SZ*H_SZ;
  const unsigned short* xz_p = xz_all + (size_t)b*T_SZ*H_SZ;
  float* out_p = out + (size_t)b*T_SZ*H_SZ;

  float br = 0.f, bz = 0.f, bn = 0.f, hj = 0.f;
  if(g == 2){ br = bhr[j]; bz = bhz[j]; bn = bhN[j]; }
  if(tid < 256) hs16[tid] = 0;
  __syncthreads();

  for(int t = 0; t < T_SZ; ++t){
    float xr = 0.f, xz = 0.f, xn = 0.f;
    if(g == 2){
      xr = h2f(xr_p[t*256 + j]);
      xz = h2f(xz_p[t*256 + j]);
      xn = out_p[t*256 + j];        // read xn before overwriting with h
    }
    float a0 = 0.f, a1 = 0.f, a2 = 0.f, a3 = 0.f;
    #pragma unroll
    for(int q = 0; q < 32; ++q){
      uint4 hq = *(const uint4*)&hs16[q*8];   // broadcast read, 8 h values
      a0 = dot2acc(wreg[q].x, hq.x, a0);
      a1 = dot2acc(wreg[q].y, hq.y, a1);
      a2 = dot2acc(wreg[q].z, hq.z, a2);
      a3 = dot2acc(wreg[q].w, hq.w, a3);
    }
    float s = (a0 + a1) + (a2 + a3);
    if(g == 0)      pr[j] = s;
    else if(g == 1) pz[j] = s;
    __syncthreads();
    if(g == 2){
      float r  = sigmoidf_(xr + br + pr[j]);
      float z  = sigmoidf_(xz + bz + pz[j]);
      float n  = tanhf_(xn + r*(s + bn));
      float hn = (1.f - z)*n + z*hj;
      hj = hn;
      out_p[t*256 + j] = hn;
      hs16[j] = f2h(hn);
    }
    __syncthreads();
  }
  if(g == 2) hlast[b*256 + j] = hj;
}

extern "C" void kernel_launch(void* const* d_in, const int* in_sizes, int n_in,
                              void* d_out, int out_size, void* d_ws, size_t ws_size,
                              hipStream_t stream){
  const float* X   = (const float*)d_in[0];
  const float* Wir = (const float*)d_in[1];
  const float* bir = (const float*)d_in[2];
  const float* Whr = (const float*)d_in[3];
  const float* bhr = (const float*)d_in[4];
  const float* Wiz = (const float*)d_in[5];
  const float* biz = (const float*)d_in[6];
  const float* Whz = (const float*)d_in[7];
  const float* bhz = (const float*)d_in[8];
  const float* WiN = (const float*)d_in[9];
  const float* biN = (const float*)d_in[10];
  const float* WhN = (const float*)d_in[11];
  const float* bhN = (const float*)d_in[12];

  float* out   = (float*)d_out;
  float* hlast = out + (size_t)B_SZ*T_SZ*H_SZ;

  unsigned char* ws = (unsigned char*)d_ws;
  unsigned short* xr = (unsigned short*)ws;                                   // 67.1 MB f16
  unsigned short* xz = (unsigned short*)(ws + (size_t)B_SZ*T_SZ*H_SZ*2);      // 67.1 MB f16
  uint4* WP = (uint4*)(ws + (size_t)B_SZ*T_SZ*H_SZ*4);                        // 384 KB

  prep_pack<<<3, 256, 0, stream>>>(Whr, Whz, WhN, WP);
  proj_kernel<<<2048, 256, 0, stream>>>(X, Wir, bir, xr, nullptr);
  proj_kernel<<<2048, 256, 0, stream>>>(X, Wiz, biz, xz, nullptr);
  proj_kernel<<<2048, 256, 0, stream>>>(X, WiN, biN, nullptr, out);   // xn fp32 in d_out
  scan_kernel<<<64, 768, 0, stream>>>(WP, xr, xz, out, hlast, bhr, bhz, bhN);
}